// Round 1
// baseline (370.265 us; speedup 1.0000x reference)
//
#include <hip/hip_runtime.h>
#include <math.h>

// Problem shape (fixed by the reference):
//   q: [NB, DK] fp32, k: [NB, L, DK] fp32, v: [NB, L, DV] fp32
//   out0: [NB, DV] fp32, out1 (attn): [NB, L] fp32  (concatenated in d_out)
#define NB 1024
#define L  2048
#define DK 128
#define DV 128

static constexpr float INV_TEMP = 0.088388347648318447f; // 1/sqrt(128)

// One block per batch row. 512 threads = 8 waves.
// Phase 1: scores[l] = <q, k[l]> / temp  (32 lanes per row, float4 loads)
// Phase 2: softmax over L in LDS, write attn (coalesced)
// Phase 3: out[d] = sum_l p[l] * v[l,d]  (64 lanes over d, float2 loads)
__global__ void mvsdpa_kernel(const float* __restrict__ q,
                              const float* __restrict__ k,
                              const float* __restrict__ v,
                              float* __restrict__ out,    // [NB, DV]
                              float* __restrict__ attn)   // [NB, L]
{
    const int b    = blockIdx.x;
    const int tid  = threadIdx.x;       // 0..511
    const int wave = tid >> 6;          // 0..7
    const int lane = tid & 63;
    const int half = lane >> 5;         // 0/1: which row of the pair
    const int l32  = lane & 31;         // lane within 32-group (covers DK via float4)

    __shared__ float s_scores[L];        // 8 KB: raw scores, then probabilities
    __shared__ float s_red[16];          // cross-wave reduction scratch
    __shared__ float s_partial[8][DV];   // 4 KB: per-wave PV partials

    const float* qb = q + (size_t)b * DK;
    const float* kb = k + (size_t)b * (size_t)L * DK;
    const float* vb = v + (size_t)b * (size_t)L * DV;

    // ---- Phase 1: QK^T ----
    // Each 32-lane half-wave owns one l per iteration; 16 rows in flight per block.
    const float4 q4 = *reinterpret_cast<const float4*>(qb + l32 * 4);
    for (int l = wave * 2 + half; l < L; l += 16) {
        const float4 k4 = *reinterpret_cast<const float4*>(kb + (size_t)l * DK + l32 * 4);
        float acc = q4.x * k4.x + q4.y * k4.y + q4.z * k4.z + q4.w * k4.w;
        // butterfly reduce over the 32-lane group (xor masks < 32 stay in-group)
        acc += __shfl_xor(acc, 1);
        acc += __shfl_xor(acc, 2);
        acc += __shfl_xor(acc, 4);
        acc += __shfl_xor(acc, 8);
        acc += __shfl_xor(acc, 16);
        if (l32 == 0) s_scores[l] = acc * INV_TEMP;
    }
    __syncthreads();

    // ---- Phase 2: softmax over L (2048) ----
    float vals[4];
    float lmax = -INFINITY;
    #pragma unroll
    for (int i = 0; i < 4; ++i) {
        vals[i] = s_scores[tid + i * 512];
        lmax = fmaxf(lmax, vals[i]);
    }
    #pragma unroll
    for (int m = 1; m < 64; m <<= 1) lmax = fmaxf(lmax, __shfl_xor(lmax, m));
    if (lane == 0) s_red[wave] = lmax;
    __syncthreads();
    float bmax = s_red[0];
    #pragma unroll
    for (int w = 1; w < 8; ++w) bmax = fmaxf(bmax, s_red[w]);

    float lsum = 0.f;
    #pragma unroll
    for (int i = 0; i < 4; ++i) {
        vals[i] = __expf(vals[i] - bmax);
        lsum += vals[i];
    }
    #pragma unroll
    for (int m = 1; m < 64; m <<= 1) lsum += __shfl_xor(lsum, m);
    if (lane == 0) s_red[8 + wave] = lsum;   // disjoint from s_red[0..7]
    __syncthreads();
    float bsum = 0.f;
    #pragma unroll
    for (int w = 0; w < 8; ++w) bsum += s_red[8 + w];
    const float inv = 1.0f / bsum;

    float* attn_b = attn + (size_t)b * L;
    #pragma unroll
    for (int i = 0; i < 4; ++i) {
        const float p = vals[i] * inv;
        s_scores[tid + i * 512] = p;       // reuse LDS for phase 3
        attn_b[tid + i * 512] = p;         // coalesced global store
    }
    __syncthreads();

    // ---- Phase 3: PV ----
    float2 acc2 = make_float2(0.f, 0.f);
    for (int l = wave; l < L; l += 8) {
        const float  p  = s_scores[l];
        const float2 v2 = *reinterpret_cast<const float2*>(vb + (size_t)l * DV + lane * 2);
        acc2.x += p * v2.x;
        acc2.y += p * v2.y;
    }
    reinterpret_cast<float2*>(s_partial[wave])[lane] = acc2;  // ds_write_b64
    __syncthreads();
    if (tid < DV) {
        float s = 0.f;
        #pragma unroll
        for (int w = 0; w < 8; ++w) s += s_partial[w][tid];
        out[(size_t)b * DV + tid] = s;
    }
}

extern "C" void kernel_launch(void* const* d_in, const int* in_sizes, int n_in,
                              void* d_out, int out_size, void* d_ws, size_t ws_size,
                              hipStream_t stream) {
    const float* q = (const float*)d_in[0];
    const float* k = (const float*)d_in[1];
    const float* v = (const float*)d_in[2];
    float* out  = (float*)d_out;                  // [NB, DV]
    float* attn = (float*)d_out + (size_t)NB * DV; // [NB, L]
    mvsdpa_kernel<<<NB, 512, 0, stream>>>(q, k, v, out, attn);
}